// Round 15
// baseline (592.783 us; speedup 1.0000x reference)
//
#include <hip/hip_runtime.h>
#include <cmath>

#define DEV __device__ __forceinline__

namespace {

constexpr int Kp    = 127;          // patch tokens
constexpr int Mrows = 32 * Kp;      // 4064 = B*K
constexpr int Rred  = 128 * Kp;     // 16256 = D*K (flat reduction length)

DEV float q88(float x) {
  float r = rintf(x * 256.0f);                       // round half to even, like jnp.round
  r = fminf(fmaxf(r, -32768.0f), 32767.0f);
  return r * 0.00390625f;
}
DEV float sigmoid_(float x) { return 1.0f / (1.0f + expf(-x)); }

DEV void fma16(const float4 av, const float4 bv, float (&acc)[4][4]) {
  acc[0][0] = fmaf(av.x, bv.x, acc[0][0]); acc[0][1] = fmaf(av.x, bv.y, acc[0][1]);
  acc[0][2] = fmaf(av.x, bv.z, acc[0][2]); acc[0][3] = fmaf(av.x, bv.w, acc[0][3]);
  acc[1][0] = fmaf(av.y, bv.x, acc[1][0]); acc[1][1] = fmaf(av.y, bv.y, acc[1][1]);
  acc[1][2] = fmaf(av.y, bv.z, acc[1][2]); acc[1][3] = fmaf(av.y, bv.w, acc[1][3]);
  acc[2][0] = fmaf(av.z, bv.x, acc[2][0]); acc[2][1] = fmaf(av.z, bv.y, acc[2][1]);
  acc[2][2] = fmaf(av.z, bv.z, acc[2][2]); acc[2][3] = fmaf(av.z, bv.w, acc[2][3]);
  acc[3][0] = fmaf(av.w, bv.x, acc[3][0]); acc[3][1] = fmaf(av.w, bv.y, acc[3][1]);
  acc[3][2] = fmaf(av.w, bv.z, acc[3][2]); acc[3][3] = fmaf(av.w, bv.w, acc[3][3]);
}

// fma 2 rows x 4 cols
DEV void fma8(const float2 av, const float4 bv, float (&acc)[2][4]) {
  acc[0][0] = fmaf(av.x, bv.x, acc[0][0]); acc[0][1] = fmaf(av.x, bv.y, acc[0][1]);
  acc[0][2] = fmaf(av.x, bv.z, acc[0][2]); acc[0][3] = fmaf(av.x, bv.w, acc[0][3]);
  acc[1][0] = fmaf(av.y, bv.x, acc[1][0]); acc[1][1] = fmaf(av.y, bv.y, acc[1][1]);
  acc[1][2] = fmaf(av.y, bv.z, acc[1][2]); acc[1][3] = fmaf(av.y, bv.w, acc[1][3]);
}

// ---------------- K0: prep = w8t transpose-quant + small-weight quant + 1x1 proj --------------
// blocks [0,6096): w8t tile;  [6096,7134): small-weight quant;  [7134,9182): proj conv.
__global__ __launch_bounds__(256) void k_prep(
    const float* __restrict__ wf, int* __restrict__ w8t,
    const float* __restrict__ wpatch, const float* __restrict__ bpatch,
    const float* __restrict__ whead, const float* __restrict__ bhead,
    const float* __restrict__ bflat,
    float* __restrict__ wpq, float* __restrict__ bq_patch,
    float* __restrict__ wq_head, float* __restrict__ bq_head, float* __restrict__ bq_flat,
    const float* __restrict__ x, const float* __restrict__ wproj,
    const float* __restrict__ bproj, float* __restrict__ xpq) {
  int bid = blockIdx.x;
  int tid = threadIdx.x;
  if (bid < 6096) {
    __shared__ __align__(16) float Ts[64][132];
    int r0 = (bid % 254) * 64, o0 = (bid / 254) * 128;
    for (int e = tid; e < 2048; e += 256) {
      int ol = e >> 4, rq = e & 15;
      float4 v = *reinterpret_cast<const float4*>(wf + (size_t)(o0 + ol) * Rred + r0 + rq * 4);
      Ts[rq * 4 + 0][ol] = v.x;
      Ts[rq * 4 + 1][ol] = v.y;
      Ts[rq * 4 + 2][ol] = v.z;
      Ts[rq * 4 + 3][ol] = v.w;
    }
    __syncthreads();
    for (int e = tid; e < 512; e += 256) {
      int rl = e >> 3, s8 = e & 7;
      int words[4];
#pragma unroll
      for (int k = 0; k < 4; ++k) {
        float4 v = *reinterpret_cast<const float4*>(&Ts[rl][s8 * 16 + k * 4]);
        int b0 = (int)fminf(fmaxf(rintf(v.x * 256.0f), -127.0f), 127.0f);
        int b1 = (int)fminf(fmaxf(rintf(v.y * 256.0f), -127.0f), 127.0f);
        int b2 = (int)fminf(fmaxf(rintf(v.z * 256.0f), -127.0f), 127.0f);
        int b3 = (int)fminf(fmaxf(rintf(v.w * 256.0f), -127.0f), 127.0f);
        words[k] = (b0 & 0xFF) | ((b1 & 0xFF) << 8) | ((b2 & 0xFF) << 16) | ((b3 & 0xFF) << 24);
      }
      *reinterpret_cast<int4*>(w8t + (size_t)(r0 + rl) * 768 + (o0 >> 2) + s8 * 4) =
          make_int4(words[0], words[1], words[2], words[3]);
    }
  } else if (bid < 7134) {
    int i = (bid - 6096) * 256 + tid;
    if (i < 262144) {
      int j = i >> 14;
      int c = (i >> 7) & 127;
      int d = i & 127;
      wpq[i] = q88(wpatch[(d * 128 + c) * 16 + j]);   // w_patch[d][c][j] -> wpq[j][c][d]
    }
    int t = i - 262144;
    if (t >= 0) {
      if      (t < 128)  bq_patch[t]        = q88(bpatch[t]);
      else if (t < 384)  wq_head[t - 128]   = q88(whead[t - 128]);
      else if (t < 386)  bq_head[t - 384]   = q88(bhead[t - 384]);
      else if (t < 3458) bq_flat[t - 386]   = q88(bflat[t - 386]);
    }
  } else {
    __shared__ float xs[128];
    int bl0 = (bid - 7134) * 16;
    if (tid < 128) xs[tid] = q88(x[(size_t)bl0 * 8 + tid]);
    __syncthreads();
    int o = tid & 127;
    int half = tid >> 7;
    float wv[8];
#pragma unroll
    for (int c = 0; c < 8; ++c) wv[c] = q88(wproj[o * 8 + c]);
    float bb = q88(bproj[o]);
#pragma unroll
    for (int il = 0; il < 8; ++il) {
      int l_loc = half * 8 + il;
      float acc = bb;
#pragma unroll
      for (int c = 0; c < 8; ++c) acc = fmaf(xs[l_loc * 8 + c], wv[c], acc);
      xpq[(size_t)(bl0 + l_loc) * 128 + o] = q88(acc);
    }
  }
}

// ---------------- K2: patch conv as 16 accumulated GEMMs, j-split x4 -------------------------
__global__ __launch_bounds__(256) void k_patch(const float* __restrict__ xpq, const float* __restrict__ wpq,
                                               float* __restrict__ partJ) {
  __shared__ __align__(16) float As[128][36];
  int mt = blockIdx.x, jg = blockIdx.y;
  int tid = threadIdx.x;
  int mr = tid & 31, c0 = (tid >> 5) * 16;
  int tn = tid & 31, tm8 = tid >> 5;
  int m0 = mt * 32;
  int g = m0 + mr;
  int bb = g / 127, kq = g % 127;
  float acc[4][4] = {};
  for (int jj = 0; jj < 4; ++jj) {
    int j = jg * 4 + jj;
    const float* src = xpq + ((size_t)bb * 1024 + kq * 8 + j) * 128 + c0;
    __syncthreads();
#pragma unroll
    for (int q = 0; q < 4; ++q) {
      float4 v = *reinterpret_cast<const float4*>(src + q * 4);
      As[c0 + q * 4 + 0][mr] = v.x;
      As[c0 + q * 4 + 1][mr] = v.y;
      As[c0 + q * 4 + 2][mr] = v.z;
      As[c0 + q * 4 + 3][mr] = v.w;
    }
    __syncthreads();
    const float* wp = wpq + (size_t)j * 16384 + tn * 4;
#pragma unroll 4
    for (int c = 0; c < 128; ++c) {
      float4 bv = *reinterpret_cast<const float4*>(wp + c * 128);
      float4 av = *reinterpret_cast<const float4*>(&As[c][tm8 * 4]);
      fma16(av, bv, acc);
    }
  }
  float* dst = partJ + ((size_t)jg * Mrows + m0) * 128 + tn * 4;
#pragma unroll
  for (int i = 0; i < 4; ++i) {
    float4 o4 = make_float4(acc[i][0], acc[i][1], acc[i][2], acc[i][3]);
    *reinterpret_cast<float4*>(dst + (size_t)(tm8 * 4 + i) * 128) = o4;
  }
}

// ---------------- K3: combine j-partials + bias, q88, add positional encoding ----------------
__global__ __launch_bounds__(256) void k_combine(const float* __restrict__ partJ, const float* __restrict__ bqp,
                                                 const float* __restrict__ pe, const float* __restrict__ pesc,
                                                 float* __restrict__ h) {
  int i = blockIdx.x * 256 + threadIdx.x;  // < 520192
  int n = i & 127;
  int gq = i >> 7;
  int k = gq % 127;
  float s = partJ[i] + partJ[520192 + i] + partJ[2 * 520192 + i] + partJ[3 * 520192 + i] + bqp[n];
  h[i] = q88(s) + pesc[0] * pe[k * 128 + n];
}

// ---------------- K4: LN + u/g GEMMs + silu, 16-row tile (254 blocks) -------------------------
__global__ __launch_bounds__(256) void k_ln_ug2(const float* __restrict__ h, const float* __restrict__ lng,
                                                const float* __restrict__ lnb, const float* __restrict__ Win,
                                                const float* __restrict__ Wgate, float* __restrict__ u,
                                                float* __restrict__ gbuf) {
  __shared__ __align__(16) float As[128][20];
  __shared__ float2 lnpart[16][16];
  __shared__ float mean_s[16], inv_s[16];
  int tid = threadIdx.x;
  int mr = tid & 15, cg = tid >> 4;
  int c0 = cg * 8;
  int m0 = blockIdx.x * 16;
  const float* src = h + (size_t)(m0 + mr) * 128 + c0;
  float4 v0 = *reinterpret_cast<const float4*>(src);
  float4 v1 = *reinterpret_cast<const float4*>(src + 4);
  float a[8] = {v0.x, v0.y, v0.z, v0.w, v1.x, v1.y, v1.z, v1.w};
  float s1 = 0.f, s2 = 0.f;
#pragma unroll
  for (int i = 0; i < 8; ++i) {
    As[c0 + i][mr] = a[i];
    s1 += a[i];
    s2 = fmaf(a[i], a[i], s2);
  }
  lnpart[cg][mr] = make_float2(s1, s2);
  __syncthreads();
  if (tid < 16) {
    float s = 0.f, ss = 0.f;
#pragma unroll
    for (int j = 0; j < 16; ++j) { float2 p = lnpart[j][tid]; s += p.x; ss += p.y; }
    float mn = s * (1.0f / 128.0f);
    mean_s[tid] = mn;
    inv_s[tid] = rsqrtf(ss * (1.0f / 128.0f) - mn * mn + 1e-5f);
  }
  __syncthreads();
  {
    float mnv = mean_s[mr], invv = inv_s[mr];
#pragma unroll
    for (int i = 0; i < 8; ++i) {
      int c = c0 + i;
      As[c][mr] = (a[i] - mnv) * invv * lng[c] + lnb[c];
    }
  }
  __syncthreads();
  int tn = tid & 31, tm = tid >> 5;           // 2 rows x 4 cols per thread
  float accU[2][4] = {}, accG[2][4] = {};
  const float* wpU = Win + tn * 4;
  const float* wpG = Wgate + tn * 4;
#pragma unroll 4
  for (int c = 0; c < 128; ++c) {
    float2 av = *reinterpret_cast<const float2*>(&As[c][tm * 2]);
    float4 bu = *reinterpret_cast<const float4*>(wpU + c * 128);
    fma8(av, bu, accU);
    float4 bg = *reinterpret_cast<const float4*>(wpG + c * 128);
    fma8(av, bg, accG);
  }
#pragma unroll
  for (int i = 0; i < 2; ++i) {
    int row = m0 + tm * 2 + i;
    float4 o4;
    { float xq = q88(accU[i][0]); o4.x = q88(xq * sigmoid_(xq)); }
    { float xq = q88(accU[i][1]); o4.y = q88(xq * sigmoid_(xq)); }
    { float xq = q88(accU[i][2]); o4.z = q88(xq * sigmoid_(xq)); }
    { float xq = q88(accU[i][3]); o4.w = q88(xq * sigmoid_(xq)); }
    *reinterpret_cast<float4*>(u + (size_t)row * 128 + tn * 4) = o4;
    float4 g4;
    { float xq = q88(accG[i][0]); g4.x = q88(xq * sigmoid_(xq)); }
    { float xq = q88(accG[i][1]); g4.y = q88(xq * sigmoid_(xq)); }
    { float xq = q88(accG[i][2]); g4.z = q88(xq * sigmoid_(xq)); }
    { float xq = q88(accG[i][3]); g4.w = q88(xq * sigmoid_(xq)); }
    *reinterpret_cast<float4*>(gbuf + (size_t)row * 128 + tn * 4) = g4;
  }
}

// ---------------- K5: lam GEMM, 16-t tile (grid 32x8 = 256 blocks) ----------------------------
__global__ __launch_bounds__(256) void k_lamg(const float* __restrict__ u, const float* __restrict__ wdt,
                                              const float* __restrict__ bdt, float* __restrict__ lam) {
  __shared__ __align__(16) float Wk[32][20];    // [k][t], 16 t
  __shared__ __align__(16) float Us[32][132];   // [k][d]
  int b = blockIdx.x, tt = blockIdx.y;
  int t0 = tt * 16;
  int tid = threadIdx.x;
  int dg = tid & 31, tg = tid >> 5;   // out: t = t0 + tg*2 + ti, d = dg*4 + di
  float acc[2][4] = {};
  const float* ub = u + (size_t)b * (127 * 128);
  for (int k0 = 0; k0 < 127; k0 += 32) {
    __syncthreads();
    {
#pragma unroll
      for (int e = tid; e < 512; e += 256) {
        int k = e & 31, t = e >> 5;
        int tg2 = t0 + t, kg = k0 + k;
        Wk[k][t] = (tg2 < 127 && kg < 127) ? wdt[tg2 * 127 + kg] : 0.f;
      }
    }
    {
      int dq = tid & 7, k = tid >> 3;
      int kg = k0 + k;
      const float* srcp = ub + (size_t)kg * 128 + dq * 16;
#pragma unroll
      for (int q = 0; q < 4; ++q) {
        float4 v = make_float4(0.f, 0.f, 0.f, 0.f);
        if (kg < 127) v = *reinterpret_cast<const float4*>(srcp + q * 4);
        *reinterpret_cast<float4*>(&Us[k][dq * 16 + q * 4]) = v;
      }
    }
    __syncthreads();
#pragma unroll 4
    for (int k = 0; k < 32; ++k) {
      float2 tv = *reinterpret_cast<const float2*>(&Wk[k][tg * 2]);
      float4 dv = *reinterpret_cast<const float4*>(&Us[k][dg * 4]);
      fma8(tv, dv, acc);
    }
  }
#pragma unroll
  for (int ti = 0; ti < 2; ++ti) {
    int t = t0 + tg * 2 + ti;
    if (t < 127) {
      float bb = bdt[t];
      float4 o4;
      o4.x = q88(sigmoid_(q88(acc[ti][0] + bb)));
      o4.y = q88(sigmoid_(q88(acc[ti][1] + bb)));
      o4.z = q88(sigmoid_(q88(acc[ti][2] + bb)));
      o4.w = q88(sigmoid_(q88(acc[ti][3] + bb)));
      *reinterpret_cast<float4*>(lam + ((size_t)b * 127 + t) * 128 + dg * 4) = o4;
    }
  }
}

// ---------------- K6: sequential scan + p = y*g; 1 block per batch, thread per d -------------
__global__ __launch_bounds__(128) void k_scan(const float* __restrict__ u, const float* __restrict__ gbuf,
                                              float* __restrict__ lamp) {
  int b = blockIdx.x, d = threadIdx.x;
  const size_t base = (size_t)b * (127 * 128) + d;
  float lm[8], uu[8], gg[8];
#pragma unroll
  for (int j = 0; j < 8; ++j) {
    size_t idx = base + (size_t)j * 128;
    lm[j] = lamp[idx]; uu[j] = u[idx]; gg[j] = gbuf[idx];
  }
  float s = 0.f;
  int t = 0;
  for (int it = 0; it < 15; ++it) {   // t = 0..119
#pragma unroll
    for (int j = 0; j < 8; ++j) {
      float l0 = lm[j], u0 = uu[j], g0 = gg[j];
      s = l0 * s + (1.0f - l0) * u0;
      lamp[base + (size_t)(t + j) * 128] = s * g0;
      int tn = t + j + 8;
      if (tn < 127) {
        size_t idx = base + (size_t)tn * 128;
        lm[j] = lamp[idx]; uu[j] = u[idx]; gg[j] = gbuf[idx];
      }
    }
    t += 8;
  }
#pragma unroll
  for (int j = 0; j < 7; ++j) {
    float l0 = lm[j], u0 = uu[j], g0 = gg[j];
    s = l0 * s + (1.0f - l0) * u0;
    lamp[base + (size_t)(120 + j) * 128] = s * g0;
  }
}

// ---------------- K7: fused (h += p@Wout) -> LN -> u/g GEMMs, 16-row tile (254 blocks) --------
__global__ __launch_bounds__(256) void k_out_ln_ug(
    const float* __restrict__ p, const float* __restrict__ Wout, float* __restrict__ h,
    const float* __restrict__ lng, const float* __restrict__ lnb,
    const float* __restrict__ Win, const float* __restrict__ Wgate,
    float* __restrict__ u, float* __restrict__ gbuf) {
  __shared__ __align__(16) float As[128][20];
  __shared__ float2 lnpart[16][16];
  __shared__ float mean_s[16], inv_s[16];
  int tid = threadIdx.x;
  int mr = tid & 15, cg = tid >> 4;
  int c0 = cg * 8;
  int m0 = blockIdx.x * 16;
  // stage p (transposed)
  {
    const float* src = p + (size_t)(m0 + mr) * 128 + c0;
    float4 v0 = *reinterpret_cast<const float4*>(src);
    float4 v1 = *reinterpret_cast<const float4*>(src + 4);
    As[c0 + 0][mr] = v0.x; As[c0 + 1][mr] = v0.y; As[c0 + 2][mr] = v0.z; As[c0 + 3][mr] = v0.w;
    As[c0 + 4][mr] = v1.x; As[c0 + 5][mr] = v1.y; As[c0 + 6][mr] = v1.z; As[c0 + 7][mr] = v1.w;
  }
  __syncthreads();
  int tn = tid & 31, tm = tid >> 5;
  float acc[2][4] = {};
  {
    const float* wp = Wout + tn * 4;
#pragma unroll 4
    for (int c = 0; c < 128; ++c) {
      float2 av = *reinterpret_cast<const float2*>(&As[c][tm * 2]);
      float4 bv = *reinterpret_cast<const float4*>(wp + c * 128);
      fma8(av, bv, acc);
    }
  }
  // hv = h + acc; write back h
  float4 hv[2];
#pragma unroll
  for (int i = 0; i < 2; ++i) {
    float* hdst = h + (size_t)(m0 + tm * 2 + i) * 128 + tn * 4;
    hv[i] = *reinterpret_cast<float4*>(hdst);
    hv[i].x += acc[i][0]; hv[i].y += acc[i][1]; hv[i].z += acc[i][2]; hv[i].w += acc[i][3];
    *reinterpret_cast<float4*>(hdst) = hv[i];
  }
  __syncthreads();                 // all GEMM reads of As done
  // restage hv transposed
#pragma unroll
  for (int i = 0; i < 2; ++i) {
    int row = tm * 2 + i;
    As[tn * 4 + 0][row] = hv[i].x;
    As[tn * 4 + 1][row] = hv[i].y;
    As[tn * 4 + 2][row] = hv[i].z;
    As[tn * 4 + 3][row] = hv[i].w;
  }
  __syncthreads();
  // LN stats
  float a[8];
  {
    float s1 = 0.f, s2 = 0.f;
#pragma unroll
    for (int i = 0; i < 8; ++i) {
      a[i] = As[c0 + i][mr];
      s1 += a[i];
      s2 = fmaf(a[i], a[i], s2);
    }
    lnpart[cg][mr] = make_float2(s1, s2);
  }
  __syncthreads();
  if (tid < 16) {
    float s = 0.f, ss = 0.f;
#pragma unroll
    for (int j = 0; j < 16; ++j) { float2 pp = lnpart[j][tid]; s += pp.x; ss += pp.y; }
    float mn = s * (1.0f / 128.0f);
    mean_s[tid] = mn;
    inv_s[tid] = rsqrtf(ss * (1.0f / 128.0f) - mn * mn + 1e-5f);
  }
  __syncthreads();
  {
    float mnv = mean_s[mr], invv = inv_s[mr];
#pragma unroll
    for (int i = 0; i < 8; ++i) {
      int c = c0 + i;
      As[c][mr] = (a[i] - mnv) * invv * lng[c] + lnb[c];
    }
  }
  __syncthreads();
  float accU[2][4] = {}, accG[2][4] = {};
  const float* wpU = Win + tn * 4;
  const float* wpG = Wgate + tn * 4;
#pragma unroll 4
  for (int c = 0; c < 128; ++c) {
    float2 av = *reinterpret_cast<const float2*>(&As[c][tm * 2]);
    float4 bu = *reinterpret_cast<const float4*>(wpU + c * 128);
    fma8(av, bu, accU);
    float4 bg = *reinterpret_cast<const float4*>(wpG + c * 128);
    fma8(av, bg, accG);
  }
#pragma unroll
  for (int i = 0; i < 2; ++i) {
    int row = m0 + tm * 2 + i;
    float4 o4;
    { float xq = q88(accU[i][0]); o4.x = q88(xq * sigmoid_(xq)); }
    { float xq = q88(accU[i][1]); o4.y = q88(xq * sigmoid_(xq)); }
    { float xq = q88(accU[i][2]); o4.z = q88(xq * sigmoid_(xq)); }
    { float xq = q88(accU[i][3]); o4.w = q88(xq * sigmoid_(xq)); }
    *reinterpret_cast<float4*>(u + (size_t)row * 128 + tn * 4) = o4;
    float4 g4;
    { float xq = q88(accG[i][0]); g4.x = q88(xq * sigmoid_(xq)); }
    { float xq = q88(accG[i][1]); g4.y = q88(xq * sigmoid_(xq)); }
    { float xq = q88(accG[i][2]); g4.z = q88(xq * sigmoid_(xq)); }
    { float xq = q88(accG[i][3]); g4.w = q88(xq * sigmoid_(xq)); }
    *reinterpret_cast<float4*>(gbuf + (size_t)row * 128 + tn * 4) = g4;
  }
}

// ---------------- K8: fused (h += p@Wout) -> final LN -> q88 -> transpose, 16-row tile --------
__global__ __launch_bounds__(256) void k_out_lnf(
    const float* __restrict__ p, const float* __restrict__ Wout, const float* __restrict__ h,
    const float* __restrict__ gg, const float* __restrict__ bb, float* __restrict__ xp2q) {
  __shared__ __align__(16) float As[128][20];
  __shared__ float2 lnpart[16][16];
  __shared__ float mean_s[16], inv_s[16];
  int tid = threadIdx.x;
  int mr = tid & 15, cg = tid >> 4;
  int c0 = cg * 8;
  int m0 = blockIdx.x * 16;
  {
    const float* src = p + (size_t)(m0 + mr) * 128 + c0;
    float4 v0 = *reinterpret_cast<const float4*>(src);
    float4 v1 = *reinterpret_cast<const float4*>(src + 4);
    As[c0 + 0][mr] = v0.x; As[c0 + 1][mr] = v0.y; As[c0 + 2][mr] = v0.z; As[c0 + 3][mr] = v0.w;
    As[c0 + 4][mr] = v1.x; As[c0 + 5][mr] = v1.y; As[c0 + 6][mr] = v1.z; As[c0 + 7][mr] = v1.w;
  }
  __syncthreads();
  int tn = tid & 31, tm = tid >> 5;
  float acc[2][4] = {};
  {
    const float* wp = Wout + tn * 4;
#pragma unroll 4
    for (int c = 0; c < 128; ++c) {
      float2 av = *reinterpret_cast<const float2*>(&As[c][tm * 2]);
      float4 bv = *reinterpret_cast<const float4*>(wp + c * 128);
      fma8(av, bv, acc);
    }
  }
  float4 hv[2];
#pragma unroll
  for (int i = 0; i < 2; ++i) {
    const float* hsrc = h + (size_t)(m0 + tm * 2 + i) * 128 + tn * 4;
    hv[i] = *reinterpret_cast<const float4*>(hsrc);
    hv[i].x += acc[i][0]; hv[i].y += acc[i][1]; hv[i].z += acc[i][2]; hv[i].w += acc[i][3];
  }
  __syncthreads();
#pragma unroll
  for (int i = 0; i < 2; ++i) {
    int row = tm * 2 + i;
    As[tn * 4 + 0][row] = hv[i].x;
    As[tn * 4 + 1][row] = hv[i].y;
    As[tn * 4 + 2][row] = hv[i].z;
    As[tn * 4 + 3][row] = hv[i].w;
  }
  __syncthreads();
  float a[8];
  {
    float s1 = 0.f, s2 = 0.f;
#pragma unroll
    for (int i = 0; i < 8; ++i) {
      a[i] = As[c0 + i][mr];
      s1 += a[i];
      s2 = fmaf(a[i], a[i], s2);
    }
    lnpart[cg][mr] = make_float2(s1, s2);
  }
  __syncthreads();
  if (tid < 16) {
    float s = 0.f, ss = 0.f;
#pragma unroll
    for (int j = 0; j < 16; ++j) { float2 pp = lnpart[j][tid]; s += pp.x; ss += pp.y; }
    float mn = s * (1.0f / 128.0f);
    mean_s[tid] = mn;
    inv_s[tid] = rsqrtf(ss * (1.0f / 128.0f) - mn * mn + 1e-5f);
  }
  __syncthreads();
  {
    float mnv = mean_s[mr], invv = inv_s[mr];
    int row = m0 + mr;
    int b = row / 127, k = row % 127;
#pragma unroll
    for (int i = 0; i < 8; ++i) {
      int c = c0 + i;
      float hn = (a[i] - mnv) * invv * gg[c] + bb[c];
      xp2q[((size_t)b * 128 + c) * 127 + k] = q88(hn);
    }
  }
}

// ---------------- K9: flat contraction v8 (transposed int8 W, coalesced) ---------------------
__global__ __launch_bounds__(256) void k_flat(const float* __restrict__ Aq, const int* __restrict__ W8t,
                                              float* __restrict__ partF) {
  __shared__ __align__(16) float As[32][36];    // [r][b] raw
  __shared__ __align__(16) float Ws[32][260];   // [r][o] decoded int8
  int ot = blockIdx.x, rs = blockIdx.y;
  int tid = threadIdx.x;
  int og = tid & 63, bsub = tid >> 6;
  int o0 = ot * 256;
  int r0 = rs * 128;               // 127*128 = 16256 exact, no guards
  float acc[8][4] = {};

  const int ab = tid >> 3, arq = tid & 7;        // A staging
  const int rhalf = tid >> 4, oseg = tid & 15;   // W staging

  int4 wreg[2];
  float4 areg;

  auto loadch = [&](int chn) {
    int rbase = r0 + chn * 32;
#pragma unroll
    for (int q = 0; q < 2; ++q) {
      int row = rbase + rhalf + q * 16;
      wreg[q] = *reinterpret_cast<const int4*>(W8t + (size_t)row * 768 + (o0 >> 2) + oseg * 4);
    }
    areg = *reinterpret_cast<const float4*>(Aq + (size_t)ab * Rred + rbase + arq * 4);
  };

  loadch(0);
  for (int ch = 0; ch < 4; ++ch) {
    __syncthreads();
#pragma unroll
    for (int q = 0; q < 2; ++q) {
      int rl = rhalf + q * 16;
      int col = oseg * 16;
      int w[4] = {wreg[q].x, wreg[q].y, wreg[q].z, wreg[q].w};
#pragma unroll
      for (int k = 0; k < 4; ++k) {
        int wv = w[k];
        float4 f;
        f.x = (float)((wv << 24) >> 24);
        f.y = (float)((wv << 16) >> 24);
        f.z = (float)((wv << 8) >> 24);
        f.w = (float)(wv >> 24);
        *reinterpret_cast<float4*>(&Ws[rl][col + k * 4]) = f;
      }
    }
    {
      int rl = arq * 4;
      As[rl + 0][ab] = areg.x;
      As[rl + 1][ab] = areg.y;
      As[rl + 2][ab] = areg.z;
      As[rl + 3][ab] = areg.w;
    }
    __syncthreads();
    if (ch < 3) loadch(ch + 1);
#pragma unroll 4
    for (int rl = 0; rl < 32; ++rl) {
      float4 w  = *reinterpret_cast<const float4*>(&Ws[rl][og * 4]);
      float4 a0 = *reinterpret_cast<const float4*>(&As[rl][bsub * 8]);
      float4 a1 = *reinterpret_cast<const float4*>(&As[rl][bsub * 8 + 4]);
      float a[8] = {a0.x, a0.y, a0.z, a0.w, a1.x, a1.y, a1.z, a1.w};
#pragma unroll
      for (int bi = 0; bi < 8; ++bi) {
        acc[bi][0] = fmaf(a[bi], w.x, acc[bi][0]);
        acc[bi][1] = fmaf(a[bi], w.y, acc[bi][1]);
        acc[bi][2] = fmaf(a[bi], w.z, acc[bi][2]);
        acc[bi][3] = fmaf(a[bi], w.w, acc[bi][3]);
      }
    }
  }
#pragma unroll
  for (int bi = 0; bi < 8; ++bi) {
    int b = bsub * 8 + bi;
    float* dst = partF + ((size_t)rs * 32 + b) * 3072 + o0 + og * 4;
    *reinterpret_cast<float4*>(dst) = make_float4(acc[bi][0] * 0.00390625f, acc[bi][1] * 0.00390625f,
                                                  acc[bi][2] * 0.00390625f, acc[bi][3] * 0.00390625f);
  }
}

// ---------------- K10: reduce 127 partials -> y_feat (q88) -> head conv1x1 (merged) ----------
__global__ __launch_bounds__(256) void k_head(const float* __restrict__ partF, const float* __restrict__ bqf,
                                              const float* __restrict__ wqh, const float* __restrict__ bqh,
                                              float* __restrict__ out) {
  int b = blockIdx.x;
  int tid = threadIdx.x;
  __shared__ float yf[3072];
#pragma unroll
  for (int i = 0; i < 12; ++i) {
    int o = tid + 256 * i;
    float s = bqf[o];
    for (int r = 0; r < 127; ++r) s += partF[((size_t)r * 32 + b) * 3072 + o];
    yf[o] = q88(s);
  }
  __syncthreads();
  if (tid < 48) {
    int oh = tid / 24, f = tid % 24;
    float acc = bqh[oh];
    for (int d = 0; d < 128; ++d) acc = fmaf(yf[d * 24 + f], wqh[oh * 128 + d], acc);
    out[(size_t)b * 48 + oh * 24 + f] = q88(acc);
  }
}

}  // namespace

extern "C" void kernel_launch(void* const* d_in, const int* in_sizes, int n_in,
                              void* d_out, int out_size, void* d_ws, size_t ws_size,
                              hipStream_t stream) {
  const float* x      = (const float*)d_in[0];
  const float* wproj  = (const float*)d_in[1];
  const float* bproj  = (const float*)d_in[2];
  const float* wpatch = (const float*)d_in[3];
  const float* bpatch = (const float*)d_in[4];
  const float* pe     = (const float*)d_in[5];
  const float* pescal = (const float*)d_in[6];
  const float* lng    = (const float*)d_in[7];
  const float* lnb    = (const float*)d_in[8];
  const float* win    = (const float*)d_in[9];
  const float* wgate  = (const float*)d_in[10];
  const float* wout   = (const float*)d_in[11];
  const float* wdt    = (const float*)d_in[12];
  const float* bdt    = (const float*)d_in[13];
  const float* lnfg   = (const float*)d_in[14];
  const float* lnfb   = (const float*)d_in[15];
  const float* wflat  = (const float*)d_in[16];
  const float* bflat  = (const float*)d_in[17];
  const float* whead  = (const float*)d_in[18];
  const float* bhead  = (const float*)d_in[19];
  float* out = (float*)d_out;
  float* ws  = (float*)d_ws;

  // ws layout (float offsets)
  constexpr size_t O_WPQ     = 2048;      // 262144   [j][c][d]
  constexpr size_t O_BQPATCH = 264192;    // 128
  constexpr size_t O_WQHEAD  = 264320;    // 256
  constexpr size_t O_BQHEAD  = 264576;    // 2 (pad 128)
  constexpr size_t O_BQFLAT  = 264704;    // 3072
  constexpr size_t O_XPQ     = 267776;    // 4194304  [b][l][c]
  constexpr size_t O_PARTJ   = 4462080;   // 4*520192
  constexpr size_t O_H       = 6542848;   // 520192   [b][k][d]
  constexpr size_t O_U       = 7063040;   // 520192
  constexpr size_t O_G       = 7583232;   // 520192
  constexpr size_t O_P       = 8103424;   // 520192   lam, then p = y*g
  constexpr size_t O_XP2Q    = 8623616;   // 520192   [b][r] (= [b][d][k])
  constexpr size_t O_PARTF   = 9143808;   // 127*98304 = 12472320
  constexpr size_t O_W8T     = 21825024;  // 12484608 dwords (int8 W transposed [r][o])

  k_prep<<<9182, 256, 0, stream>>>(wflat, (int*)(ws + O_W8T),
                                   wpatch, bpatch, whead, bhead, bflat,
                                   ws + O_WPQ, ws + O_BQPATCH, ws + O_WQHEAD,
                                   ws + O_BQHEAD, ws + O_BQFLAT,
                                   x, wproj, bproj, ws + O_XPQ);

  {
    dim3 g(127, 4);
    k_patch<<<g, 256, 0, stream>>>(ws + O_XPQ, ws + O_WPQ, ws + O_PARTJ);
  }
  k_combine<<<2032, 256, 0, stream>>>(ws + O_PARTJ, ws + O_BQPATCH, pe, pescal, ws + O_H);

  k_ln_ug2<<<254, 256, 0, stream>>>(ws + O_H, lng, lnb, win, wgate, ws + O_U, ws + O_G);

  for (int i = 0; i < 4; ++i) {
    {
      dim3 gl(32, 8);
      k_lamg<<<gl, 256, 0, stream>>>(ws + O_U, wdt + (size_t)i * 16129, bdt + (size_t)i * 127,
                                     ws + O_P);
    }
    k_scan<<<32, 128, 0, stream>>>(ws + O_U, ws + O_G, ws + O_P);
    if (i < 3) {
      k_out_ln_ug<<<254, 256, 0, stream>>>(ws + O_P, wout + (size_t)i * 16384, ws + O_H,
                                           lng + (i + 1) * 128, lnb + (i + 1) * 128,
                                           win + (size_t)(i + 1) * 16384,
                                           wgate + (size_t)(i + 1) * 16384,
                                           ws + O_U, ws + O_G);
    } else {
      k_out_lnf<<<254, 256, 0, stream>>>(ws + O_P, wout + (size_t)i * 16384, ws + O_H,
                                         lnfg, lnfb, ws + O_XP2Q);
    }
  }

  {
    dim3 g(12, 127);
    k_flat<<<g, 256, 0, stream>>>(ws + O_XP2Q, (const int*)(ws + O_W8T), ws + O_PARTF);
  }
  k_head<<<32, 256, 0, stream>>>(ws + O_PARTF, ws + O_BQFLAT, ws + O_WQHEAD, ws + O_BQHEAD, out);
}

// Round 16
// 406.551 us; speedup vs baseline: 1.4581x; 1.4581x over previous
//
#include <hip/hip_runtime.h>
#include <cmath>

#define DEV __device__ __forceinline__

namespace {

constexpr int Kp    = 127;          // patch tokens
constexpr int Mrows = 32 * Kp;      // 4064 = B*K
constexpr int Rred  = 128 * Kp;     // 16256 = D*K (flat reduction length)

DEV float q88(float x) {
  float r = rintf(x * 256.0f);                       // round half to even, like jnp.round
  r = fminf(fmaxf(r, -32768.0f), 32767.0f);
  return r * 0.00390625f;
}
DEV float sigmoid_(float x) { return 1.0f / (1.0f + expf(-x)); }

DEV void fma16(const float4 av, const float4 bv, float (&acc)[4][4]) {
  acc[0][0] = fmaf(av.x, bv.x, acc[0][0]); acc[0][1] = fmaf(av.x, bv.y, acc[0][1]);
  acc[0][2] = fmaf(av.x, bv.z, acc[0][2]); acc[0][3] = fmaf(av.x, bv.w, acc[0][3]);
  acc[1][0] = fmaf(av.y, bv.x, acc[1][0]); acc[1][1] = fmaf(av.y, bv.y, acc[1][1]);
  acc[1][2] = fmaf(av.y, bv.z, acc[1][2]); acc[1][3] = fmaf(av.y, bv.w, acc[1][3]);
  acc[2][0] = fmaf(av.z, bv.x, acc[2][0]); acc[2][1] = fmaf(av.z, bv.y, acc[2][1]);
  acc[2][2] = fmaf(av.z, bv.z, acc[2][2]); acc[2][3] = fmaf(av.z, bv.w, acc[2][3]);
  acc[3][0] = fmaf(av.w, bv.x, acc[3][0]); acc[3][1] = fmaf(av.w, bv.y, acc[3][1]);
  acc[3][2] = fmaf(av.w, bv.z, acc[3][2]); acc[3][3] = fmaf(av.w, bv.w, acc[3][3]);
}

// fma 2 rows x 4 cols
DEV void fma8(const float2 av, const float4 bv, float (&acc)[2][4]) {
  acc[0][0] = fmaf(av.x, bv.x, acc[0][0]); acc[0][1] = fmaf(av.x, bv.y, acc[0][1]);
  acc[0][2] = fmaf(av.x, bv.z, acc[0][2]); acc[0][3] = fmaf(av.x, bv.w, acc[0][3]);
  acc[1][0] = fmaf(av.y, bv.x, acc[1][0]); acc[1][1] = fmaf(av.y, bv.y, acc[1][1]);
  acc[1][2] = fmaf(av.y, bv.z, acc[1][2]); acc[1][3] = fmaf(av.y, bv.w, acc[1][3]);
}

// ---------------- K0: prep = w8t transpose-quant + small-weight quant + 1x1 proj --------------
// blocks [0,6096): w8t tile;  [6096,7134): small-weight quant;  [7134,9182): proj conv.
__global__ __launch_bounds__(256) void k_prep(
    const float* __restrict__ wf, int* __restrict__ w8t,
    const float* __restrict__ wpatch, const float* __restrict__ bpatch,
    const float* __restrict__ whead, const float* __restrict__ bhead,
    const float* __restrict__ bflat,
    float* __restrict__ wpq, float* __restrict__ bq_patch,
    float* __restrict__ wq_head, float* __restrict__ bq_head, float* __restrict__ bq_flat,
    const float* __restrict__ x, const float* __restrict__ wproj,
    const float* __restrict__ bproj, float* __restrict__ xpq) {
  int bid = blockIdx.x;
  int tid = threadIdx.x;
  if (bid < 6096) {
    __shared__ __align__(16) float Ts[64][132];
    int r0 = (bid % 254) * 64, o0 = (bid / 254) * 128;
    for (int e = tid; e < 2048; e += 256) {
      int ol = e >> 4, rq = e & 15;
      float4 v = *reinterpret_cast<const float4*>(wf + (size_t)(o0 + ol) * Rred + r0 + rq * 4);
      Ts[rq * 4 + 0][ol] = v.x;
      Ts[rq * 4 + 1][ol] = v.y;
      Ts[rq * 4 + 2][ol] = v.z;
      Ts[rq * 4 + 3][ol] = v.w;
    }
    __syncthreads();
    for (int e = tid; e < 512; e += 256) {
      int rl = e >> 3, s8 = e & 7;
      int words[4];
#pragma unroll
      for (int k = 0; k < 4; ++k) {
        float4 v = *reinterpret_cast<const float4*>(&Ts[rl][s8 * 16 + k * 4]);
        int b0 = (int)fminf(fmaxf(rintf(v.x * 256.0f), -127.0f), 127.0f);
        int b1 = (int)fminf(fmaxf(rintf(v.y * 256.0f), -127.0f), 127.0f);
        int b2 = (int)fminf(fmaxf(rintf(v.z * 256.0f), -127.0f), 127.0f);
        int b3 = (int)fminf(fmaxf(rintf(v.w * 256.0f), -127.0f), 127.0f);
        words[k] = (b0 & 0xFF) | ((b1 & 0xFF) << 8) | ((b2 & 0xFF) << 16) | ((b3 & 0xFF) << 24);
      }
      *reinterpret_cast<int4*>(w8t + (size_t)(r0 + rl) * 768 + (o0 >> 2) + s8 * 4) =
          make_int4(words[0], words[1], words[2], words[3]);
    }
  } else if (bid < 7134) {
    int i = (bid - 6096) * 256 + tid;
    if (i < 262144) {
      int j = i >> 14;
      int c = (i >> 7) & 127;
      int d = i & 127;
      wpq[i] = q88(wpatch[(d * 128 + c) * 16 + j]);   // w_patch[d][c][j] -> wpq[j][c][d]
    }
    int t = i - 262144;
    if (t >= 0) {
      if      (t < 128)  bq_patch[t]        = q88(bpatch[t]);
      else if (t < 384)  wq_head[t - 128]   = q88(whead[t - 128]);
      else if (t < 386)  bq_head[t - 384]   = q88(bhead[t - 384]);
      else if (t < 3458) bq_flat[t - 386]   = q88(bflat[t - 386]);
    }
  } else {
    __shared__ float xs[128];
    int bl0 = (bid - 7134) * 16;
    if (tid < 128) xs[tid] = q88(x[(size_t)bl0 * 8 + tid]);
    __syncthreads();
    int o = tid & 127;
    int half = tid >> 7;
    float wv[8];
#pragma unroll
    for (int c = 0; c < 8; ++c) wv[c] = q88(wproj[o * 8 + c]);
    float bb = q88(bproj[o]);
#pragma unroll
    for (int il = 0; il < 8; ++il) {
      int l_loc = half * 8 + il;
      float acc = bb;
#pragma unroll
      for (int c = 0; c < 8; ++c) acc = fmaf(xs[l_loc * 8 + c], wv[c], acc);
      xpq[(size_t)(bl0 + l_loc) * 128 + o] = q88(acc);
    }
  }
}

// ---------------- K2: patch conv as 16 accumulated GEMMs, j-split x4 -------------------------
__global__ __launch_bounds__(256) void k_patch(const float* __restrict__ xpq, const float* __restrict__ wpq,
                                               float* __restrict__ partJ) {
  __shared__ __align__(16) float As[128][36];
  int mt = blockIdx.x, jg = blockIdx.y;
  int tid = threadIdx.x;
  int mr = tid & 31, c0 = (tid >> 5) * 16;
  int tn = tid & 31, tm8 = tid >> 5;
  int m0 = mt * 32;
  int g = m0 + mr;
  int bb = g / 127, kq = g % 127;
  float acc[4][4] = {};
  for (int jj = 0; jj < 4; ++jj) {
    int j = jg * 4 + jj;
    const float* src = xpq + ((size_t)bb * 1024 + kq * 8 + j) * 128 + c0;
    __syncthreads();
#pragma unroll
    for (int q = 0; q < 4; ++q) {
      float4 v = *reinterpret_cast<const float4*>(src + q * 4);
      As[c0 + q * 4 + 0][mr] = v.x;
      As[c0 + q * 4 + 1][mr] = v.y;
      As[c0 + q * 4 + 2][mr] = v.z;
      As[c0 + q * 4 + 3][mr] = v.w;
    }
    __syncthreads();
    const float* wp = wpq + (size_t)j * 16384 + tn * 4;
#pragma unroll 4
    for (int c = 0; c < 128; ++c) {
      float4 bv = *reinterpret_cast<const float4*>(wp + c * 128);
      float4 av = *reinterpret_cast<const float4*>(&As[c][tm8 * 4]);
      fma16(av, bv, acc);
    }
  }
  float* dst = partJ + ((size_t)jg * Mrows + m0) * 128 + tn * 4;
#pragma unroll
  for (int i = 0; i < 4; ++i) {
    float4 o4 = make_float4(acc[i][0], acc[i][1], acc[i][2], acc[i][3]);
    *reinterpret_cast<float4*>(dst + (size_t)(tm8 * 4 + i) * 128) = o4;
  }
}

// ---------------- K3: combine j-partials + bias, q88, add positional encoding ----------------
__global__ __launch_bounds__(256) void k_combine(const float* __restrict__ partJ, const float* __restrict__ bqp,
                                                 const float* __restrict__ pe, const float* __restrict__ pesc,
                                                 float* __restrict__ h) {
  int i = blockIdx.x * 256 + threadIdx.x;  // < 520192
  int n = i & 127;
  int gq = i >> 7;
  int k = gq % 127;
  float s = partJ[i] + partJ[520192 + i] + partJ[2 * 520192 + i] + partJ[3 * 520192 + i] + bqp[n];
  h[i] = q88(s) + pesc[0] * pe[k * 128 + n];
}

// ---------------- K4: LN + u/g GEMMs + silu, 16-row tile (254 blocks) -------------------------
__global__ __launch_bounds__(256) void k_ln_ug2(const float* __restrict__ h, const float* __restrict__ lng,
                                                const float* __restrict__ lnb, const float* __restrict__ Win,
                                                const float* __restrict__ Wgate, float* __restrict__ u,
                                                float* __restrict__ gbuf) {
  __shared__ __align__(16) float As[128][20];
  __shared__ float2 lnpart[16][16];
  __shared__ float mean_s[16], inv_s[16];
  int tid = threadIdx.x;
  int mr = tid & 15, cg = tid >> 4;
  int c0 = cg * 8;
  int m0 = blockIdx.x * 16;
  const float* src = h + (size_t)(m0 + mr) * 128 + c0;
  float4 v0 = *reinterpret_cast<const float4*>(src);
  float4 v1 = *reinterpret_cast<const float4*>(src + 4);
  float a[8] = {v0.x, v0.y, v0.z, v0.w, v1.x, v1.y, v1.z, v1.w};
  float s1 = 0.f, s2 = 0.f;
#pragma unroll
  for (int i = 0; i < 8; ++i) {
    As[c0 + i][mr] = a[i];
    s1 += a[i];
    s2 = fmaf(a[i], a[i], s2);
  }
  lnpart[cg][mr] = make_float2(s1, s2);
  __syncthreads();
  if (tid < 16) {
    float s = 0.f, ss = 0.f;
#pragma unroll
    for (int j = 0; j < 16; ++j) { float2 p = lnpart[j][tid]; s += p.x; ss += p.y; }
    float mn = s * (1.0f / 128.0f);
    mean_s[tid] = mn;
    inv_s[tid] = rsqrtf(ss * (1.0f / 128.0f) - mn * mn + 1e-5f);
  }
  __syncthreads();
  {
    float mnv = mean_s[mr], invv = inv_s[mr];
#pragma unroll
    for (int i = 0; i < 8; ++i) {
      int c = c0 + i;
      As[c][mr] = (a[i] - mnv) * invv * lng[c] + lnb[c];
    }
  }
  __syncthreads();
  int tn = tid & 31, tm = tid >> 5;           // 2 rows x 4 cols per thread
  float accU[2][4] = {}, accG[2][4] = {};
  const float* wpU = Win + tn * 4;
  const float* wpG = Wgate + tn * 4;
#pragma unroll 4
  for (int c = 0; c < 128; ++c) {
    float2 av = *reinterpret_cast<const float2*>(&As[c][tm * 2]);
    float4 bu = *reinterpret_cast<const float4*>(wpU + c * 128);
    fma8(av, bu, accU);
    float4 bg = *reinterpret_cast<const float4*>(wpG + c * 128);
    fma8(av, bg, accG);
  }
#pragma unroll
  for (int i = 0; i < 2; ++i) {
    int row = m0 + tm * 2 + i;
    float4 o4;
    { float xq = q88(accU[i][0]); o4.x = q88(xq * sigmoid_(xq)); }
    { float xq = q88(accU[i][1]); o4.y = q88(xq * sigmoid_(xq)); }
    { float xq = q88(accU[i][2]); o4.z = q88(xq * sigmoid_(xq)); }
    { float xq = q88(accU[i][3]); o4.w = q88(xq * sigmoid_(xq)); }
    *reinterpret_cast<float4*>(u + (size_t)row * 128 + tn * 4) = o4;
    float4 g4;
    { float xq = q88(accG[i][0]); g4.x = q88(xq * sigmoid_(xq)); }
    { float xq = q88(accG[i][1]); g4.y = q88(xq * sigmoid_(xq)); }
    { float xq = q88(accG[i][2]); g4.z = q88(xq * sigmoid_(xq)); }
    { float xq = q88(accG[i][3]); g4.w = q88(xq * sigmoid_(xq)); }
    *reinterpret_cast<float4*>(gbuf + (size_t)row * 128 + tn * 4) = g4;
  }
}

// ---------------- K5: lam GEMM, 16-t tile (grid 32x8 = 256 blocks) ----------------------------
__global__ __launch_bounds__(256) void k_lamg(const float* __restrict__ u, const float* __restrict__ wdt,
                                              const float* __restrict__ bdt, float* __restrict__ lam) {
  __shared__ __align__(16) float Wk[32][20];    // [k][t], 16 t
  __shared__ __align__(16) float Us[32][132];   // [k][d]
  int b = blockIdx.x, tt = blockIdx.y;
  int t0 = tt * 16;
  int tid = threadIdx.x;
  int dg = tid & 31, tg = tid >> 5;   // out: t = t0 + tg*2 + ti, d = dg*4 + di
  float acc[2][4] = {};
  const float* ub = u + (size_t)b * (127 * 128);
  for (int k0 = 0; k0 < 127; k0 += 32) {
    __syncthreads();
    {
#pragma unroll
      for (int e = tid; e < 512; e += 256) {
        int k = e & 31, t = e >> 5;
        int tg2 = t0 + t, kg = k0 + k;
        Wk[k][t] = (tg2 < 127 && kg < 127) ? wdt[tg2 * 127 + kg] : 0.f;
      }
    }
    {
      int dq = tid & 7, k = tid >> 3;
      int kg = k0 + k;
      const float* srcp = ub + (size_t)kg * 128 + dq * 16;
#pragma unroll
      for (int q = 0; q < 4; ++q) {
        float4 v = make_float4(0.f, 0.f, 0.f, 0.f);
        if (kg < 127) v = *reinterpret_cast<const float4*>(srcp + q * 4);
        *reinterpret_cast<float4*>(&Us[k][dq * 16 + q * 4]) = v;
      }
    }
    __syncthreads();
#pragma unroll 4
    for (int k = 0; k < 32; ++k) {
      float2 tv = *reinterpret_cast<const float2*>(&Wk[k][tg * 2]);
      float4 dv = *reinterpret_cast<const float4*>(&Us[k][dg * 4]);
      fma8(tv, dv, acc);
    }
  }
#pragma unroll
  for (int ti = 0; ti < 2; ++ti) {
    int t = t0 + tg * 2 + ti;
    if (t < 127) {
      float bb = bdt[t];
      float4 o4;
      o4.x = q88(sigmoid_(q88(acc[ti][0] + bb)));
      o4.y = q88(sigmoid_(q88(acc[ti][1] + bb)));
      o4.z = q88(sigmoid_(q88(acc[ti][2] + bb)));
      o4.w = q88(sigmoid_(q88(acc[ti][3] + bb)));
      *reinterpret_cast<float4*>(lam + ((size_t)b * 127 + t) * 128 + dg * 4) = o4;
    }
  }
}

// ---------------- K6: sequential scan + p = y*g; 1 block per batch, thread per d -------------
__global__ __launch_bounds__(128) void k_scan(const float* __restrict__ u, const float* __restrict__ gbuf,
                                              float* __restrict__ lamp) {
  int b = blockIdx.x, d = threadIdx.x;
  const size_t base = (size_t)b * (127 * 128) + d;
  float lm[8], uu[8], gg[8];
#pragma unroll
  for (int j = 0; j < 8; ++j) {
    size_t idx = base + (size_t)j * 128;
    lm[j] = lamp[idx]; uu[j] = u[idx]; gg[j] = gbuf[idx];
  }
  float s = 0.f;
  int t = 0;
  for (int it = 0; it < 15; ++it) {   // t = 0..119
#pragma unroll
    for (int j = 0; j < 8; ++j) {
      float l0 = lm[j], u0 = uu[j], g0 = gg[j];
      s = l0 * s + (1.0f - l0) * u0;
      lamp[base + (size_t)(t + j) * 128] = s * g0;
      int tn = t + j + 8;
      if (tn < 127) {
        size_t idx = base + (size_t)tn * 128;
        lm[j] = lamp[idx]; uu[j] = u[idx]; gg[j] = gbuf[idx];
      }
    }
    t += 8;
  }
#pragma unroll
  for (int j = 0; j < 7; ++j) {
    float l0 = lm[j], u0 = uu[j], g0 = gg[j];
    s = l0 * s + (1.0f - l0) * u0;
    lamp[base + (size_t)(120 + j) * 128] = s * g0;
  }
}

// ---------------- K7: fused (h += p@Wout) -> LN -> u/g GEMMs, 16-row tile (254 blocks) --------
__global__ __launch_bounds__(256) void k_out_ln_ug(
    const float* __restrict__ p, const float* __restrict__ Wout, float* __restrict__ h,
    const float* __restrict__ lng, const float* __restrict__ lnb,
    const float* __restrict__ Win, const float* __restrict__ Wgate,
    float* __restrict__ u, float* __restrict__ gbuf) {
  __shared__ __align__(16) float As[128][20];
  __shared__ float2 lnpart[16][16];
  __shared__ float mean_s[16], inv_s[16];
  int tid = threadIdx.x;
  int mr = tid & 15, cg = tid >> 4;
  int c0 = cg * 8;
  int m0 = blockIdx.x * 16;
  // stage p (transposed)
  {
    const float* src = p + (size_t)(m0 + mr) * 128 + c0;
    float4 v0 = *reinterpret_cast<const float4*>(src);
    float4 v1 = *reinterpret_cast<const float4*>(src + 4);
    As[c0 + 0][mr] = v0.x; As[c0 + 1][mr] = v0.y; As[c0 + 2][mr] = v0.z; As[c0 + 3][mr] = v0.w;
    As[c0 + 4][mr] = v1.x; As[c0 + 5][mr] = v1.y; As[c0 + 6][mr] = v1.z; As[c0 + 7][mr] = v1.w;
  }
  __syncthreads();
  int tn = tid & 31, tm = tid >> 5;
  float acc[2][4] = {};
  {
    const float* wp = Wout + tn * 4;
#pragma unroll 4
    for (int c = 0; c < 128; ++c) {
      float2 av = *reinterpret_cast<const float2*>(&As[c][tm * 2]);
      float4 bv = *reinterpret_cast<const float4*>(wp + c * 128);
      fma8(av, bv, acc);
    }
  }
  // hv = h + acc; write back h
  float4 hv[2];
#pragma unroll
  for (int i = 0; i < 2; ++i) {
    float* hdst = h + (size_t)(m0 + tm * 2 + i) * 128 + tn * 4;
    hv[i] = *reinterpret_cast<float4*>(hdst);
    hv[i].x += acc[i][0]; hv[i].y += acc[i][1]; hv[i].z += acc[i][2]; hv[i].w += acc[i][3];
    *reinterpret_cast<float4*>(hdst) = hv[i];
  }
  __syncthreads();                 // all GEMM reads of As done
  // restage hv transposed
#pragma unroll
  for (int i = 0; i < 2; ++i) {
    int row = tm * 2 + i;
    As[tn * 4 + 0][row] = hv[i].x;
    As[tn * 4 + 1][row] = hv[i].y;
    As[tn * 4 + 2][row] = hv[i].z;
    As[tn * 4 + 3][row] = hv[i].w;
  }
  __syncthreads();
  // LN stats
  float a[8];
  {
    float s1 = 0.f, s2 = 0.f;
#pragma unroll
    for (int i = 0; i < 8; ++i) {
      a[i] = As[c0 + i][mr];
      s1 += a[i];
      s2 = fmaf(a[i], a[i], s2);
    }
    lnpart[cg][mr] = make_float2(s1, s2);
  }
  __syncthreads();
  if (tid < 16) {
    float s = 0.f, ss = 0.f;
#pragma unroll
    for (int j = 0; j < 16; ++j) { float2 pp = lnpart[j][tid]; s += pp.x; ss += pp.y; }
    float mn = s * (1.0f / 128.0f);
    mean_s[tid] = mn;
    inv_s[tid] = rsqrtf(ss * (1.0f / 128.0f) - mn * mn + 1e-5f);
  }
  __syncthreads();
  {
    float mnv = mean_s[mr], invv = inv_s[mr];
#pragma unroll
    for (int i = 0; i < 8; ++i) {
      int c = c0 + i;
      As[c][mr] = (a[i] - mnv) * invv * lng[c] + lnb[c];
    }
  }
  __syncthreads();
  float accU[2][4] = {}, accG[2][4] = {};
  const float* wpU = Win + tn * 4;
  const float* wpG = Wgate + tn * 4;
#pragma unroll 4
  for (int c = 0; c < 128; ++c) {
    float2 av = *reinterpret_cast<const float2*>(&As[c][tm * 2]);
    float4 bu = *reinterpret_cast<const float4*>(wpU + c * 128);
    fma8(av, bu, accU);
    float4 bg = *reinterpret_cast<const float4*>(wpG + c * 128);
    fma8(av, bg, accG);
  }
#pragma unroll
  for (int i = 0; i < 2; ++i) {
    int row = m0 + tm * 2 + i;
    float4 o4;
    { float xq = q88(accU[i][0]); o4.x = q88(xq * sigmoid_(xq)); }
    { float xq = q88(accU[i][1]); o4.y = q88(xq * sigmoid_(xq)); }
    { float xq = q88(accU[i][2]); o4.z = q88(xq * sigmoid_(xq)); }
    { float xq = q88(accU[i][3]); o4.w = q88(xq * sigmoid_(xq)); }
    *reinterpret_cast<float4*>(u + (size_t)row * 128 + tn * 4) = o4;
    float4 g4;
    { float xq = q88(accG[i][0]); g4.x = q88(xq * sigmoid_(xq)); }
    { float xq = q88(accG[i][1]); g4.y = q88(xq * sigmoid_(xq)); }
    { float xq = q88(accG[i][2]); g4.z = q88(xq * sigmoid_(xq)); }
    { float xq = q88(accG[i][3]); g4.w = q88(xq * sigmoid_(xq)); }
    *reinterpret_cast<float4*>(gbuf + (size_t)row * 128 + tn * 4) = g4;
  }
}

// ---------------- K8: fused (h += p@Wout) -> final LN -> q88 -> transpose, 16-row tile --------
__global__ __launch_bounds__(256) void k_out_lnf(
    const float* __restrict__ p, const float* __restrict__ Wout, const float* __restrict__ h,
    const float* __restrict__ gg, const float* __restrict__ bb, float* __restrict__ xp2q) {
  __shared__ __align__(16) float As[128][20];
  __shared__ float2 lnpart[16][16];
  __shared__ float mean_s[16], inv_s[16];
  int tid = threadIdx.x;
  int mr = tid & 15, cg = tid >> 4;
  int c0 = cg * 8;
  int m0 = blockIdx.x * 16;
  {
    const float* src = p + (size_t)(m0 + mr) * 128 + c0;
    float4 v0 = *reinterpret_cast<const float4*>(src);
    float4 v1 = *reinterpret_cast<const float4*>(src + 4);
    As[c0 + 0][mr] = v0.x; As[c0 + 1][mr] = v0.y; As[c0 + 2][mr] = v0.z; As[c0 + 3][mr] = v0.w;
    As[c0 + 4][mr] = v1.x; As[c0 + 5][mr] = v1.y; As[c0 + 6][mr] = v1.z; As[c0 + 7][mr] = v1.w;
  }
  __syncthreads();
  int tn = tid & 31, tm = tid >> 5;
  float acc[2][4] = {};
  {
    const float* wp = Wout + tn * 4;
#pragma unroll 4
    for (int c = 0; c < 128; ++c) {
      float2 av = *reinterpret_cast<const float2*>(&As[c][tm * 2]);
      float4 bv = *reinterpret_cast<const float4*>(wp + c * 128);
      fma8(av, bv, acc);
    }
  }
  float4 hv[2];
#pragma unroll
  for (int i = 0; i < 2; ++i) {
    const float* hsrc = h + (size_t)(m0 + tm * 2 + i) * 128 + tn * 4;
    hv[i] = *reinterpret_cast<const float4*>(hsrc);
    hv[i].x += acc[i][0]; hv[i].y += acc[i][1]; hv[i].z += acc[i][2]; hv[i].w += acc[i][3];
  }
  __syncthreads();
#pragma unroll
  for (int i = 0; i < 2; ++i) {
    int row = tm * 2 + i;
    As[tn * 4 + 0][row] = hv[i].x;
    As[tn * 4 + 1][row] = hv[i].y;
    As[tn * 4 + 2][row] = hv[i].z;
    As[tn * 4 + 3][row] = hv[i].w;
  }
  __syncthreads();
  float a[8];
  {
    float s1 = 0.f, s2 = 0.f;
#pragma unroll
    for (int i = 0; i < 8; ++i) {
      a[i] = As[c0 + i][mr];
      s1 += a[i];
      s2 = fmaf(a[i], a[i], s2);
    }
    lnpart[cg][mr] = make_float2(s1, s2);
  }
  __syncthreads();
  if (tid < 16) {
    float s = 0.f, ss = 0.f;
#pragma unroll
    for (int j = 0; j < 16; ++j) { float2 pp = lnpart[j][tid]; s += pp.x; ss += pp.y; }
    float mn = s * (1.0f / 128.0f);
    mean_s[tid] = mn;
    inv_s[tid] = rsqrtf(ss * (1.0f / 128.0f) - mn * mn + 1e-5f);
  }
  __syncthreads();
  {
    float mnv = mean_s[mr], invv = inv_s[mr];
    int row = m0 + mr;
    int b = row / 127, k = row % 127;
#pragma unroll
    for (int i = 0; i < 8; ++i) {
      int c = c0 + i;
      float hn = (a[i] - mnv) * invv * gg[c] + bb[c];
      xp2q[((size_t)b * 128 + c) * 127 + k] = q88(hn);
    }
  }
}

// ---------------- K9: flat contraction v8 (transposed int8 W, coalesced) ---------------------
__global__ __launch_bounds__(256) void k_flat(const float* __restrict__ Aq, const int* __restrict__ W8t,
                                              float* __restrict__ partF) {
  __shared__ __align__(16) float As[32][36];    // [r][b] raw
  __shared__ __align__(16) float Ws[32][260];   // [r][o] decoded int8
  int ot = blockIdx.x, rs = blockIdx.y;
  int tid = threadIdx.x;
  int og = tid & 63, bsub = tid >> 6;
  int o0 = ot * 256;
  int r0 = rs * 128;               // 127*128 = 16256 exact, no guards
  float acc[8][4] = {};

  const int ab = tid >> 3, arq = tid & 7;        // A staging
  const int rhalf = tid >> 4, oseg = tid & 15;   // W staging

  int4 wreg[2];
  float4 areg;

  auto loadch = [&](int chn) {
    int rbase = r0 + chn * 32;
#pragma unroll
    for (int q = 0; q < 2; ++q) {
      int row = rbase + rhalf + q * 16;
      wreg[q] = *reinterpret_cast<const int4*>(W8t + (size_t)row * 768 + (o0 >> 2) + oseg * 4);
    }
    areg = *reinterpret_cast<const float4*>(Aq + (size_t)ab * Rred + rbase + arq * 4);
  };

  loadch(0);
  for (int ch = 0; ch < 4; ++ch) {
    __syncthreads();
#pragma unroll
    for (int q = 0; q < 2; ++q) {
      int rl = rhalf + q * 16;
      int col = oseg * 16;
      int w[4] = {wreg[q].x, wreg[q].y, wreg[q].z, wreg[q].w};
#pragma unroll
      for (int k = 0; k < 4; ++k) {
        int wv = w[k];
        float4 f;
        f.x = (float)((wv << 24) >> 24);
        f.y = (float)((wv << 16) >> 24);
        f.z = (float)((wv << 8) >> 24);
        f.w = (float)(wv >> 24);
        *reinterpret_cast<float4*>(&Ws[rl][col + k * 4]) = f;
      }
    }
    {
      int rl = arq * 4;
      As[rl + 0][ab] = areg.x;
      As[rl + 1][ab] = areg.y;
      As[rl + 2][ab] = areg.z;
      As[rl + 3][ab] = areg.w;
    }
    __syncthreads();
    if (ch < 3) loadch(ch + 1);
#pragma unroll 4
    for (int rl = 0; rl < 32; ++rl) {
      float4 w  = *reinterpret_cast<const float4*>(&Ws[rl][og * 4]);
      float4 a0 = *reinterpret_cast<const float4*>(&As[rl][bsub * 8]);
      float4 a1 = *reinterpret_cast<const float4*>(&As[rl][bsub * 8 + 4]);
      float a[8] = {a0.x, a0.y, a0.z, a0.w, a1.x, a1.y, a1.z, a1.w};
#pragma unroll
      for (int bi = 0; bi < 8; ++bi) {
        acc[bi][0] = fmaf(a[bi], w.x, acc[bi][0]);
        acc[bi][1] = fmaf(a[bi], w.y, acc[bi][1]);
        acc[bi][2] = fmaf(a[bi], w.z, acc[bi][2]);
        acc[bi][3] = fmaf(a[bi], w.w, acc[bi][3]);
      }
    }
  }
#pragma unroll
  for (int bi = 0; bi < 8; ++bi) {
    int b = bsub * 8 + bi;
    float* dst = partF + ((size_t)rs * 32 + b) * 3072 + o0 + og * 4;
    *reinterpret_cast<float4*>(dst) = make_float4(acc[bi][0] * 0.00390625f, acc[bi][1] * 0.00390625f,
                                                  acc[bi][2] * 0.00390625f, acc[bi][3] * 0.00390625f);
  }
}

// ---------------- K10: reduce 127 r-partials + bias -> y_feat (q88) --------------------------
__global__ __launch_bounds__(256) void k_yfeat(const float* __restrict__ partF, const float* __restrict__ bqf,
                                               float* __restrict__ yf) {
  int b = blockIdx.x, oc = blockIdx.y;
  int o = oc * 256 + threadIdx.x;
  float s = bqf[o];
  for (int r = 0; r < 127; ++r) s += partF[((size_t)r * 32 + b) * 3072 + o];
  yf[(size_t)b * 3072 + o] = q88(s);
}

// ---------------- K11: head conv1x1 over y_feat ----------------------------------------------
__global__ __launch_bounds__(256) void k_head2(const float* __restrict__ yf, const float* __restrict__ wqh,
                                               const float* __restrict__ bqh, float* __restrict__ out) {
  int b = blockIdx.x;
  int tid = threadIdx.x;
  __shared__ float ys[3072];
#pragma unroll
  for (int i = 0; i < 12; ++i) ys[tid + 256 * i] = yf[(size_t)b * 3072 + tid + 256 * i];
  __syncthreads();
  if (tid < 48) {
    int oh = tid / 24, f = tid % 24;
    float acc = bqh[oh];
    for (int d = 0; d < 128; ++d) acc = fmaf(ys[d * 24 + f], wqh[oh * 128 + d], acc);
    out[(size_t)b * 48 + oh * 24 + f] = q88(acc);
  }
}

}  // namespace

extern "C" void kernel_launch(void* const* d_in, const int* in_sizes, int n_in,
                              void* d_out, int out_size, void* d_ws, size_t ws_size,
                              hipStream_t stream) {
  const float* x      = (const float*)d_in[0];
  const float* wproj  = (const float*)d_in[1];
  const float* bproj  = (const float*)d_in[2];
  const float* wpatch = (const float*)d_in[3];
  const float* bpatch = (const float*)d_in[4];
  const float* pe     = (const float*)d_in[5];
  const float* pescal = (const float*)d_in[6];
  const float* lng    = (const float*)d_in[7];
  const float* lnb    = (const float*)d_in[8];
  const float* win    = (const float*)d_in[9];
  const float* wgate  = (const float*)d_in[10];
  const float* wout   = (const float*)d_in[11];
  const float* wdt    = (const float*)d_in[12];
  const float* bdt    = (const float*)d_in[13];
  const float* lnfg   = (const float*)d_in[14];
  const float* lnfb   = (const float*)d_in[15];
  const float* wflat  = (const float*)d_in[16];
  const float* bflat  = (const float*)d_in[17];
  const float* whead  = (const float*)d_in[18];
  const float* bhead  = (const float*)d_in[19];
  float* out = (float*)d_out;
  float* ws  = (float*)d_ws;

  // ws layout (float offsets)
  constexpr size_t O_WPQ     = 2048;      // 262144   [j][c][d]
  constexpr size_t O_BQPATCH = 264192;    // 128
  constexpr size_t O_WQHEAD  = 264320;    // 256
  constexpr size_t O_BQHEAD  = 264576;    // 2 (pad 128)
  constexpr size_t O_BQFLAT  = 264704;    // 3072
  constexpr size_t O_XPQ     = 267776;    // 4194304  [b][l][c]
  constexpr size_t O_PARTJ   = 4462080;   // 4*520192
  constexpr size_t O_H       = 6542848;   // 520192   [b][k][d]
  constexpr size_t O_U       = 7063040;   // 520192
  constexpr size_t O_G       = 7583232;   // 520192
  constexpr size_t O_P       = 8103424;   // 520192   lam, then p = y*g
  constexpr size_t O_XP2Q    = 8623616;   // 520192   [b][r] (= [b][d][k])
  constexpr size_t O_PARTF   = 9143808;   // 127*98304 = 12472320
  constexpr size_t O_YF      = 21616128;  // 98304
  constexpr size_t O_W8T     = 21825024;  // 12484608 dwords (int8 W transposed [r][o])

  k_prep<<<9182, 256, 0, stream>>>(wflat, (int*)(ws + O_W8T),
                                   wpatch, bpatch, whead, bhead, bflat,
                                   ws + O_WPQ, ws + O_BQPATCH, ws + O_WQHEAD,
                                   ws + O_BQHEAD, ws + O_BQFLAT,
                                   x, wproj, bproj, ws + O_XPQ);

  {
    dim3 g(127, 4);
    k_patch<<<g, 256, 0, stream>>>(ws + O_XPQ, ws + O_WPQ, ws + O_PARTJ);
  }
  k_combine<<<2032, 256, 0, stream>>>(ws + O_PARTJ, ws + O_BQPATCH, pe, pescal, ws + O_H);

  k_ln_ug2<<<254, 256, 0, stream>>>(ws + O_H, lng, lnb, win, wgate, ws + O_U, ws + O_G);

  for (int i = 0; i < 4; ++i) {
    {
      dim3 gl(32, 8);
      k_lamg<<<gl, 256, 0, stream>>>(ws + O_U, wdt + (size_t)i * 16129, bdt + (size_t)i * 127,
                                     ws + O_P);
    }
    k_scan<<<32, 128, 0, stream>>>(ws + O_U, ws + O_G, ws + O_P);
    if (i < 3) {
      k_out_ln_ug<<<254, 256, 0, stream>>>(ws + O_P, wout + (size_t)i * 16384, ws + O_H,
                                           lng + (i + 1) * 128, lnb + (i + 1) * 128,
                                           win + (size_t)(i + 1) * 16384,
                                           wgate + (size_t)(i + 1) * 16384,
                                           ws + O_U, ws + O_G);
    } else {
      k_out_lnf<<<254, 256, 0, stream>>>(ws + O_P, wout + (size_t)i * 16384, ws + O_H,
                                         lnfg, lnfb, ws + O_XP2Q);
    }
  }

  {
    dim3 g(12, 127);
    k_flat<<<g, 256, 0, stream>>>(ws + O_XP2Q, (const int*)(ws + O_W8T), ws + O_PARTF);
  }
  {
    dim3 gy(32, 12);
    k_yfeat<<<gy, 256, 0, stream>>>(ws + O_PARTF, ws + O_BQFLAT, ws + O_YF);
  }
  k_head2<<<32, 256, 0, stream>>>(ws + O_YF, ws + O_WQHEAD, ws + O_BQHEAD, out);
}